// Round 7
// baseline (1990.994 us; speedup 1.0000x reference)
//
#include <hip/hip_runtime.h>

// x: [B=4, C=8, H=128, W=128] f32 -> out: [B, C, 210, H*W] f32
// Channels 0..44   : v[j]*v[k],        j<=k       (pairs2, i-major lex order)
// Channels 45..209 : v[i]*(v[j]*v[k]), i<=j<=k    (pairs3, i-major lex order)
//
// R7 DIAGNOSTIC ROUND. nt stores (R6) changed nothing -> L2-policy theories
// dead. Kernel time is ~151 us (graded 433.8 - 283 us harness poison-fill),
// ~2x the 75 us pure-write floor, and we have never seen the kernel's own
// counters (always < the 279 us fill cutoff in top-5). This round makes it
// visible:
//   1) hoi_store_probe: IDENTICAL grid + address multiset, stores zeros,
//      5 reps -> isolates the store path. ~355 us if store path runs at
//      fill rate (6.2 TB/s), ~750 us if stores are the 2.9 TB/s limiter.
//   2) hoi_kernel: the real R0-structure kernel, 3 reps (idempotent
//      re-stores; output exact) -> full-kernel counters.
// Probe runs FIRST; real kernel overwrites everything -> correctness kept.
// Graded time regresses this round by design; reverted next round.

#define HH 128
#define WW 128
#define LL (HH * WW)
#define NCH 210

__host__ __device__ constexpr int ch2_idx(int i, int j) {
    // pairs2 lex index, i <= j
    return i * 9 - (i * (i - 1)) / 2 + (j - i);
}
__host__ __device__ constexpr int tri(int m) { return m * (m + 1) / 2; }
__host__ __device__ constexpr int ch3_idx(int i, int j, int k) {
    // 45 + lex index of (i,j,k), i <= j <= k
    int s = 0;
    for (int a = 0; a < i; ++a) s += tri(9 - a);
    for (int b = i; b < j; ++b) s += (9 - b);
    return 45 + s + (k - j);
}

// ---------------- store-only probe: same addresses, constant data ----------
template <int JLO, int JHI>
__device__ __forceinline__ void emit_z(float4 z, float* __restrict__ obase) {
#pragma unroll
    for (int j = JLO; j < JHI; ++j) {
#pragma unroll
        for (int k = j; k < 9; ++k) {
            *reinterpret_cast<float4*>(obase + ch2_idx(j, k) * LL) = z;
#pragma unroll
            for (int i = 0; i <= j; ++i) {
                *reinterpret_cast<float4*>(obase + ch3_idx(i, j, k) * LL) = z;
            }
        }
    }
}

__global__ __launch_bounds__(256, 4) void hoi_store_probe(float* __restrict__ out) {
    const int tid   = blockIdx.x * 256 + threadIdx.x;
    const int wq    = tid & 31;
    const int h     = (tid >> 5) & 127;
    const int plane = tid >> 12;
    const int w0    = wq << 2;

    float* __restrict__ obase = out + (size_t)plane * NCH * LL + h * WW + w0;

#pragma unroll 1
    for (int rep = 0; rep < 5; ++rep) {
        // value depends on rep + memory clobber: defeats dead-store elim so
        // all 5 reps actually issue their stores.
        float4 z = make_float4((float)rep, 0.f, 0.f, 0.f);
        if (blockIdx.y == 0) {
            emit_z<0, 4>(z, obase);
        } else {
            emit_z<4, 9>(z, obase);
        }
        asm volatile("" ::: "memory");
    }
}

// ---------------- real kernel (R0 structure), 3 idempotent reps ------------
template <int JLO, int JHI>
__device__ __forceinline__ void emit(const float4 (&v)[9], float* __restrict__ obase) {
#pragma unroll
    for (int j = JLO; j < JHI; ++j) {
#pragma unroll
        for (int k = j; k < 9; ++k) {
            float4 t;
            t.x = v[j].x * v[k].x;
            t.y = v[j].y * v[k].y;
            t.z = v[j].z * v[k].z;
            t.w = v[j].w * v[k].w;
            *reinterpret_cast<float4*>(obase + ch2_idx(j, k) * LL) = t;
#pragma unroll
            for (int i = 0; i <= j; ++i) {
                float4 q;
                q.x = v[i].x * t.x;
                q.y = v[i].y * t.y;
                q.z = v[i].z * t.z;
                q.w = v[i].w * t.w;
                *reinterpret_cast<float4*>(obase + ch3_idx(i, j, k) * LL) = q;
            }
        }
    }
}

__global__ __launch_bounds__(256, 4) void hoi_kernel(const float* __restrict__ x,
                                                     float* __restrict__ out) {
    const int tid   = blockIdx.x * 256 + threadIdx.x;
    const int wq    = tid & 31;          // group of 4 columns
    const int h     = (tid >> 5) & 127;  // row
    const int plane = tid >> 12;         // b*C + c  (0..31)
    const int w0    = wq << 2;

    const float* __restrict__ xp = x + (size_t)plane * LL;

    // 3 rows x 6 cols neighborhood, zero-padded.
    float r[3][6];
#pragma unroll
    for (int dh = 0; dh < 3; ++dh) {
        const int hh = h + dh - 1;
        const bool hv = (hh >= 0) & (hh < HH);
#pragma unroll
        for (int dw = 0; dw < 6; ++dw) {
            const int ww = w0 + dw - 1;
            const bool wv = (ww >= 0) & (ww < WW);
            r[dh][dw] = (hv & wv) ? xp[hh * WW + ww] : 0.0f;
        }
    }

    // 9 taps, each a float4 sliding window over this thread's 4 pixels.
    float4 v[9];
#pragma unroll
    for (int dh = 0; dh < 3; ++dh) {
#pragma unroll
        for (int dw = 0; dw < 3; ++dw) {
            v[dh * 3 + dw] = make_float4(r[dh][dw], r[dh][dw + 1],
                                         r[dh][dw + 2], r[dh][dw + 3]);
        }
    }

    float* __restrict__ obase = out + (size_t)plane * NCH * LL + h * WW + w0;

    // 3 reps, identical correct values each time (idempotent); memory clobber
    // keeps all reps' stores live. Channel split across gridDim.y as before.
#pragma unroll 1
    for (int rep = 0; rep < 3; ++rep) {
        if (blockIdx.y == 0) {
            emit<0, 4>(v, obase);
        } else {
            emit<4, 9>(v, obase);
        }
        asm volatile("" ::: "memory");
    }
}

extern "C" void kernel_launch(void* const* d_in, const int* in_sizes, int n_in,
                              void* d_out, int out_size, void* d_ws, size_t ws_size,
                              hipStream_t stream) {
    const float* x = (const float*)d_in[0];
    float* out = (float*)d_out;

    const int nplanes = in_sizes[0] / LL;          // B*C = 32
    const int total   = nplanes * HH * (WW / 4);   // one thread per 4 pixels
    const int block   = 256;
    const int gx      = (total + block - 1) / block;

    // Probe first (writes garbage), real kernel second (overwrites with
    // correct values). Same stream -> ordered.
    hoi_store_probe<<<dim3(gx, 2), block, 0, stream>>>(out);
    hoi_kernel<<<dim3(gx, 2), block, 0, stream>>>(x, out);
}